// Round 9
// baseline (56.305 us; speedup 1.0000x reference)
//
#include <hip/hip_runtime.h>
#include <hip/hip_bf16.h>
#include <math.h>

#define TB 4096   // batch
#define TN 39     // fields
#define TM 32     // embed dim
#define TD 32     // product layer dim
#define TH 400    // hidden width
#define BN_EPS 1e-3f

#define KT0 2     // layer-0 K=64  -> 2 chunks of K32
#define KTH 13    // layers 1/2 K=400 padded to 416 -> 13 chunks of K32
#define RGB 8     // rows per gather block
#define ESP (TN * TM + 8)   // e_s row stride (pad 8 floats: bank-shift 8, 16B-aligned)

typedef __attribute__((ext_vector_type(8))) short bf16x8;
typedef __attribute__((ext_vector_type(4))) float f32x4;

// ---- fp32 -> bf16 hi/lo split ----
__device__ __forceinline__ ushort bf16_rn(float x) {
    __hip_bfloat16 h = __float2bfloat16(x);
    union { __hip_bfloat16 b; ushort u; } c; c.b = h; return c.u;
}
__device__ __forceinline__ void split2(float x, ushort& hi, ushort& lo) {
    unsigned xb = __float_as_uint(x);
    unsigned hb = xb & 0xFFFF0000u;
    hi = (ushort)(hb >> 16);
    lo = bf16_rn(x - __uint_as_float(hb));
}

// MFMA 16x16x32 bf16 fragment layout. Panels: [tile16][kt32][lane 64][j 8]
// ushorts; one (tile,kt) chunk = 512 ushorts = 1 KB.
__device__ __forceinline__ size_t panel_idx(int p, int k, int KT) {
    int lane_ = (p & 15) + 16 * ((k >> 2) & 3);
    int j_    = (k & 3) + 4 * ((k >> 4) & 1);
    return (((size_t)((p >> 4) * KT + (k >> 5)) * 64) + lane_) * 8 + j_;
}

// ---------------------------------------------------------------------------
// Front kernel v4:
//  blocks [0,512): gather (8 rows) + l_z (4x d-tiled) + l_p -> A0 panels
//  blocks [512,910): prepack W0/W1/W2 -> B panels; fold BN -> AC arrays
// ---------------------------------------------------------------------------
__global__ __launch_bounds__(256) void fused_front_kernel(
    const int*   __restrict__ fidx,
    const float* __restrict__ emb,
    const float* __restrict__ lin_w,
    const float* __restrict__ quad_w,
    const float* __restrict__ W0, const float* __restrict__ W1, const float* __restrict__ W2,
    const float* __restrict__ b0_, const float* __restrict__ g0_, const float* __restrict__ be0_,
    const float* __restrict__ rm0_, const float* __restrict__ rv0_,
    const float* __restrict__ b1_, const float* __restrict__ g1_, const float* __restrict__ be1_,
    const float* __restrict__ rm1_, const float* __restrict__ rv1_,
    const float* __restrict__ b2_, const float* __restrict__ g2_, const float* __restrict__ be2_,
    const float* __restrict__ rm2_, const float* __restrict__ rv2_,
    ushort* __restrict__ A0h, ushort* __restrict__ A0l,
    ushort* __restrict__ B0h, ushort* __restrict__ B0l,
    ushort* __restrict__ B1h, ushort* __restrict__ B1l,
    ushort* __restrict__ B2h, ushort* __restrict__ B2l,
    float* __restrict__ AC)
{
    if (blockIdx.x >= TB / RGB) {
        int tid = (blockIdx.x - TB / RGB) * 256 + threadIdx.x;
        const int NW0 = 64 * 112, NW = 416 * 112;
        if (tid < NW0 + 2 * NW) {
            const float* W; ushort *Ph, *Pl; int k, n4, K, KT;
            if (tid < NW0) {
                W = W0; Ph = B0h; Pl = B0l; k = tid / 112; n4 = tid % 112; K = 64; KT = KT0;
            } else if (tid < NW0 + NW) {
                int u = tid - NW0;
                W = W1; Ph = B1h; Pl = B1l; k = u / 112; n4 = u % 112; K = TH; KT = KTH;
            } else {
                int u = tid - NW0 - NW;
                W = W2; Ph = B2h; Pl = B2l; k = u / 112; n4 = u % 112; K = TH; KT = KTH;
            }
            int n0 = n4 * 4;
            float4 w = make_float4(0.f, 0.f, 0.f, 0.f);
            if (k < K && n0 < TH)
                w = *(const float4*)&W[(size_t)k * TH + n0];
            float vals[4] = {w.x, w.y, w.z, w.w};
            #pragma unroll
            for (int i = 0; i < 4; ++i) {
                ushort hi, lo; split2(vals[i], hi, lo);
                size_t idx = panel_idx(n0 + i, k, KT);
                Ph[idx] = hi; Pl[idx] = lo;
            }
        } else if (tid < NW0 + 2 * NW + 3 * 448) {
            int u = tid - NW0 - 2 * NW;
            int layer = u / 448, h = u % 448;
            const float *gp, *bep, *rmp, *rvp, *bp;
            if (layer == 0)      { gp = g0_; bep = be0_; rmp = rm0_; rvp = rv0_; bp = b0_; }
            else if (layer == 1) { gp = g1_; bep = be1_; rmp = rm1_; rvp = rv1_; bp = b1_; }
            else                 { gp = g2_; bep = be2_; rmp = rm2_; rvp = rv2_; bp = b2_; }
            float aj = 0.f, cj = 0.f;
            if (h < TH) {
                aj = gp[h] * rsqrtf(rvp[h] + BN_EPS);
                cj = (bp[h] - rmp[h]) * aj + bep[h];
            }
            AC[layer * 896 + h] = aj;
            AC[layer * 896 + 448 + h] = cj;
        }
        return;
    }

    // ---------------- gather + product path ----------------
    __shared__ float e_s[RGB][ESP];     // 8 x 1256 floats ~ 40 KB (padded rows)
    __shared__ int   idx_s[RGB][TN];
    __shared__ float s_s[RGB][TN];

    const int t  = threadIdx.x;
    const int b0 = blockIdx.x * RGB;

    for (int u = t; u < RGB * TN; u += 256) {
        int r = u / TN, n = u - r * TN;
        idx_s[r][n] = fidx[(b0 + r) * TN + n];
    }
    __syncthreads();

    for (int r = 0; r < RGB; ++r) {
        for (int k4 = t; k4 < TN * TM / 4; k4 += 256) {
            int n = k4 >> 3;
            long long base = (long long)idx_s[r][n] * TM + ((k4 & 7) << 2);
            *(float4*)&e_s[r][k4 * 4] = *(const float4*)&emb[base];
        }
    }
    __syncthreads();

    // l_z v4: thread (dg = t>>5, rs = (t>>3)&3, j = t&7).
    // Computes d = dg*4+{0..3} for rows r = rs*2+{0,1}; K-slice (all i, m-slot j)
    // identical to the verified round-2 order -> bitwise-identical l_z.
    {
        const int dg = t >> 5, rs = (t >> 3) & 3, j = t & 7;
        const int mo = j * 4;
        float acc[4][2] = {};
        const float* lw0 = lin_w + (size_t)(dg * 4) * (TN * TM) + mo;
        const float* er0 = &e_s[rs * 2][0];
        const float* er1 = &e_s[rs * 2 + 1][0];
        #pragma unroll 4
        for (int i = 0; i < TN; ++i) {
            float4 lw[4];
            #pragma unroll
            for (int di = 0; di < 4; ++di)
                lw[di] = *(const float4*)(lw0 + (size_t)di * (TN * TM) + i * 32);
            float4 e0 = *(const float4*)(er0 + i * 32 + mo);
            float4 e1 = *(const float4*)(er1 + i * 32 + mo);
            #pragma unroll
            for (int di = 0; di < 4; ++di) {
                acc[di][0] = fmaf(lw[di].x, e0.x, acc[di][0]);
                acc[di][0] = fmaf(lw[di].y, e0.y, acc[di][0]);
                acc[di][0] = fmaf(lw[di].z, e0.z, acc[di][0]);
                acc[di][0] = fmaf(lw[di].w, e0.w, acc[di][0]);
                acc[di][1] = fmaf(lw[di].x, e1.x, acc[di][1]);
                acc[di][1] = fmaf(lw[di].y, e1.y, acc[di][1]);
                acc[di][1] = fmaf(lw[di].z, e1.z, acc[di][1]);
                acc[di][1] = fmaf(lw[di].w, e1.w, acc[di][1]);
            }
        }
        // reduce across the 8-lane j group (same tree as verified round-2)
        #pragma unroll
        for (int off = 1; off < 8; off <<= 1)
            #pragma unroll
            for (int di = 0; di < 4; ++di)
                #pragma unroll
                for (int rr = 0; rr < 2; ++rr)
                    acc[di][rr] += __shfl_xor(acc[di][rr], off);
        if (j == 0) {
            #pragma unroll
            for (int di = 0; di < 4; ++di)
                #pragma unroll
                for (int rr = 0; rr < 2; ++rr) {
                    ushort hi, lo; split2(acc[di][rr], hi, lo);
                    size_t idx = panel_idx(b0 + rs * 2 + rr, dg * 4 + di, KT0);
                    A0h[idx] = hi; A0l[idx] = lo;
                }
        }
    }

    // s[n] = sum_m e^2 (diagonal to dodge bank conflicts), RGB=8 indexing
    {
        int r = t >> 5, sub = t & 31;
        for (int n = sub; n < TN; n += 32) {
            float s = 0.f;
            #pragma unroll
            for (int mm = 0; mm < TM; ++mm) {
                float v = e_s[r][n * TM + ((n + mm) & 31)];
                s = fmaf(v, v, s);
            }
            s_s[r][n] = s;
        }
    }
    __syncthreads();

    // l_p: r = t>>5 (0..7), d = t&31
    {
        int r = t >> 5, d = t & 31;
        float accv = 0.f;
        for (int n = 0; n < TN; ++n) {
            float q = quad_w[d * TN + n];
            accv = fmaf(s_s[r][n], q * q, accv);
        }
        ushort hi, lo; split2(accv, hi, lo);
        size_t idx = panel_idx(b0 + r, TD + d, KT0);
        A0h[idx] = hi; A0l[idx] = lo;
    }
}

// ---------------------------------------------------------------------------
// GEMM v6: 64x64 tile, 256 threads (4 waves, 2M x 2N quadrants of 32x32).
// 448 blocks/layer = 1792 waves. XCD-aware bijective swizzle.
// OUTMODE 0: BN+ReLU -> repack into next layer's A panels (via ysm transpose).
// OUTMODE 1: BN+ReLU -> dot with Wout -> per-(row, bn, nsel) partials to P.
// ---------------------------------------------------------------------------
template <int KT, int OUTMODE>
__global__ __launch_bounds__(256) void gemm_layer_v6(
    const ushort* __restrict__ Ah, const ushort* __restrict__ Al,
    const ushort* __restrict__ Bh, const ushort* __restrict__ Bl,
    const float* __restrict__ ACl,
    ushort* __restrict__ Nh, ushort* __restrict__ Nl,
    const float* __restrict__ Wout,
    float* __restrict__ P)
{
    const int lane = threadIdx.x & 63;
    const int wv   = threadIdx.x >> 6;      // 0..3
    const int msel = wv >> 1;               // M half
    const int nsel = wv & 1;                // N half

    // XCD-aware bijective swizzle over 448 blocks (bm 0..63, bn 0..6)
    const int orig = blockIdx.x;
    const int xcd  = orig & 7;
    const int slot = orig >> 3;             // 0..55
    const int bm   = (slot & 7) * 8 + xcd;  // 0..63
    const int bn   = slot >> 3;             // 0..6

    f32x4 acc[2][2];
    #pragma unroll
    for (int m = 0; m < 2; ++m)
        #pragma unroll
        for (int n = 0; n < 2; ++n)
            acc[m][n] = (f32x4){0.f, 0.f, 0.f, 0.f};

    const size_t lo8 = (size_t)lane * 8;
    const ushort* pAh = Ah + (size_t)(bm * 4 + msel * 2) * KT * 512 + lo8;
    const ushort* pAl = Al + (size_t)(bm * 4 + msel * 2) * KT * 512 + lo8;
    const ushort* pBh = Bh + (size_t)(bn * 4 + nsel * 2) * KT * 512 + lo8;
    const ushort* pBl = Bl + (size_t)(bn * 4 + nsel * 2) * KT * 512 + lo8;

    #pragma unroll 2
    for (int kt = 0; kt < KT; ++kt) {
        bf16x8 ah[2], al[2], bh[2], bl[2];
        #pragma unroll
        for (int m = 0; m < 2; ++m) {
            ah[m] = *(const bf16x8*)(pAh + (size_t)(m * KT + kt) * 512);
            al[m] = *(const bf16x8*)(pAl + (size_t)(m * KT + kt) * 512);
        }
        #pragma unroll
        for (int n = 0; n < 2; ++n) {
            bh[n] = *(const bf16x8*)(pBh + (size_t)(n * KT + kt) * 512);
            bl[n] = *(const bf16x8*)(pBl + (size_t)(n * KT + kt) * 512);
        }
        #pragma unroll
        for (int m = 0; m < 2; ++m)
            #pragma unroll
            for (int n = 0; n < 2; ++n) {
                acc[m][n] = __builtin_amdgcn_mfma_f32_16x16x32_bf16(ah[m], bh[n], acc[m][n], 0, 0, 0);
                acc[m][n] = __builtin_amdgcn_mfma_f32_16x16x32_bf16(ah[m], bl[n], acc[m][n], 0, 0, 0);
                acc[m][n] = __builtin_amdgcn_mfma_f32_16x16x32_bf16(al[m], bh[n], acc[m][n], 0, 0, 0);
            }
    }

    const int col = lane & 15, rq = (lane >> 4) << 2;

    if constexpr (OUTMODE == 0) {
        __shared__ float ysm[64][68];
        #pragma unroll
        for (int m = 0; m < 2; ++m)
            #pragma unroll
            for (int n = 0; n < 2; ++n) {
                int h = bn * 64 + (nsel * 2 + n) * 16 + col;
                float aj = ACl[h], cj = ACl[448 + h];
                #pragma unroll
                for (int r = 0; r < 4; ++r)
                    ysm[msel * 32 + m * 16 + rq + r][(nsel * 2 + n) * 16 + col] =
                        fmaxf(fmaf(acc[m][n][r], aj, cj), 0.f);
            }
        __syncthreads();

        const int ck = wv & 1;
        const int kt32 = bn * 2 + ck;
        if (kt32 < KTH) {
            #pragma unroll
            for (int mi = 0; mi < 2; ++mi) {
                int mtl = (wv >> 1) * 2 + mi;    // 0..3
                int row_l = mtl * 16 + (lane & 15);
                int kb = ck * 32 + rq;
                float4 v0 = *(const float4*)&ysm[row_l][kb];
                float4 v1 = *(const float4*)&ysm[row_l][kb + 16];
                ushort h_[8], l_[8];
                split2(v0.x, h_[0], l_[0]); split2(v0.y, h_[1], l_[1]);
                split2(v0.z, h_[2], l_[2]); split2(v0.w, h_[3], l_[3]);
                split2(v1.x, h_[4], l_[4]); split2(v1.y, h_[5], l_[5]);
                split2(v1.z, h_[6], l_[6]); split2(v1.w, h_[7], l_[7]);
                uint4 H, L;
                H.x = (uint)h_[0] | ((uint)h_[1] << 16);
                H.y = (uint)h_[2] | ((uint)h_[3] << 16);
                H.z = (uint)h_[4] | ((uint)h_[5] << 16);
                H.w = (uint)h_[6] | ((uint)h_[7] << 16);
                L.x = (uint)l_[0] | ((uint)l_[1] << 16);
                L.y = (uint)l_[2] | ((uint)l_[3] << 16);
                L.z = (uint)l_[4] | ((uint)l_[5] << 16);
                L.w = (uint)l_[6] | ((uint)l_[7] << 16);
                size_t base = (((size_t)(bm * 4 + mtl) * KTH + kt32) * 64 + lane) * 8;
                *(uint4*)(Nh + base) = H;
                *(uint4*)(Nl + base) = L;
            }
        }
    } else {
        // Fused final-layer epilogue: y = relu(bn(acc)); partial = sum_h y*Wout[h]
        float partial[2][4] = {{0.f,0.f,0.f,0.f},{0.f,0.f,0.f,0.f}};
        #pragma unroll
        for (int m = 0; m < 2; ++m)
            #pragma unroll
            for (int n = 0; n < 2; ++n) {
                int h = bn * 64 + (nsel * 2 + n) * 16 + col;
                float aj = ACl[h], cj = ACl[448 + h];
                float wv_ = (h < TH) ? Wout[h] : 0.f;
                #pragma unroll
                for (int r = 0; r < 4; ++r) {
                    float y = fmaxf(fmaf(acc[m][n][r], aj, cj), 0.f);
                    partial[m][r] = fmaf(y, wv_, partial[m][r]);
                }
            }
        #pragma unroll
        for (int off = 1; off < 16; off <<= 1)
            #pragma unroll
            for (int m = 0; m < 2; ++m)
                #pragma unroll
                for (int r = 0; r < 4; ++r)
                    partial[m][r] += __shfl_xor(partial[m][r], off);
        if (col == 0) {
            #pragma unroll
            for (int m = 0; m < 2; ++m)
                #pragma unroll
                for (int r = 0; r < 4; ++r)
                    P[(size_t)(bm * 64 + msel * 32 + m * 16 + rq + r) * 16
                      + bn * 2 + nsel] = partial[m][r];
        }
    }
}

// ---------------------------------------------------------------------------
// fin: out[row] = sigmoid(sum_{i<14} P[row][i] + bout), float4 loads
// ---------------------------------------------------------------------------
__global__ __launch_bounds__(256) void fin_kernel(
    const float* __restrict__ P, const float* __restrict__ bout,
    float* __restrict__ out)
{
    int row = blockIdx.x * 256 + threadIdx.x;
    const float4* p = (const float4*)(P + (size_t)row * 16);
    float4 p0 = p[0], p1 = p[1], p2 = p[2], p3 = p[3];
    float s = bout[0]
            + p0.x + p0.y + p0.z + p0.w
            + p1.x + p1.y + p1.z + p1.w
            + p2.x + p2.y + p2.z + p2.w
            + p3.x + p3.y;
    out[row] = 1.f / (1.f + expf(-s));
}

// ---------------------------------------------------------------------------
extern "C" void kernel_launch(void* const* d_in, const int* in_sizes, int n_in,
                              void* d_out, int out_size, void* d_ws, size_t ws_size,
                              hipStream_t stream) {
    const int*   fidx   = (const int*)  d_in[0];
    const float* emb    = (const float*)d_in[2];
    const float* lin_w  = (const float*)d_in[3];
    const float* quad_w = (const float*)d_in[4];

    const float* W0  = (const float*)d_in[5];
    const float* b0  = (const float*)d_in[6];
    const float* g0  = (const float*)d_in[7];
    const float* be0 = (const float*)d_in[8];
    const float* rm0 = (const float*)d_in[9];
    const float* rv0 = (const float*)d_in[10];

    const float* W1  = (const float*)d_in[11];
    const float* b1  = (const float*)d_in[12];
    const float* g1  = (const float*)d_in[13];
    const float* be1 = (const float*)d_in[14];
    const float* rm1 = (const float*)d_in[15];
    const float* rv1 = (const float*)d_in[16];

    const float* W2  = (const float*)d_in[17];
    const float* b2  = (const float*)d_in[18];
    const float* g2  = (const float*)d_in[19];
    const float* be2 = (const float*)d_in[20];
    const float* rm2 = (const float*)d_in[21];
    const float* rv2 = (const float*)d_in[22];

    const float* Wout = (const float*)d_in[23];
    const float* bout = (const float*)d_in[24];

    const size_t SZ_A0 = (size_t)256 * KT0 * 512;
    const size_t SZ_A  = (size_t)256 * KTH * 512;
    const size_t SZ_B0 = (size_t)28  * KT0 * 512;
    const size_t SZ_B  = (size_t)28  * KTH * 512;

    ushort* p = (ushort*)d_ws;
    ushort *A0h = p; p += SZ_A0; ushort *A0l = p; p += SZ_A0;
    ushort *A1h = p; p += SZ_A;  ushort *A1l = p; p += SZ_A;
    ushort *A2h = p; p += SZ_A;  ushort *A2l = p; p += SZ_A;
    ushort *B0h = p; p += SZ_B0; ushort *B0l = p; p += SZ_B0;
    ushort *B1h = p; p += SZ_B;  ushort *B1l = p; p += SZ_B;
    ushort *B2h = p; p += SZ_B;  ushort *B2l = p; p += SZ_B;
    float*  AC  = (float*)p;                 // 3 * 896 floats
    float*  Pst = AC + 3 * 896;              // 4096 x 16 partials

    fused_front_kernel<<<TB / RGB + 398, 256, 0, stream>>>(
        fidx, emb, lin_w, quad_w, W0, W1, W2,
        b0, g0, be0, rm0, rv0,
        b1, g1, be1, rm1, rv1,
        b2, g2, be2, rm2, rv2,
        A0h, A0l, B0h, B0l, B1h, B1l, B2h, B2l, AC);

    gemm_layer_v6<KT0, 0><<<448, 256, 0, stream>>>(
        A0h, A0l, B0h, B0l, AC + 0, A1h, A1l, nullptr, nullptr);
    gemm_layer_v6<KTH, 0><<<448, 256, 0, stream>>>(
        A1h, A1l, B1h, B1l, AC + 896, A2h, A2l, nullptr, nullptr);
    gemm_layer_v6<KTH, 1><<<448, 256, 0, stream>>>(
        A2h, A2l, B2h, B2l, AC + 1792, nullptr, nullptr, Wout, Pst);

    fin_kernel<<<TB / 256, 256, 0, stream>>>(Pst, bout, (float*)d_out);
}

// Round 10
// 47.272 us; speedup vs baseline: 1.1911x; 1.1911x over previous
//
#include <hip/hip_runtime.h>
#include <hip/hip_bf16.h>
#include <math.h>

#define TB 4096   // batch
#define TN 39     // fields
#define TM 32     // embed dim
#define TD 32     // product layer dim
#define TH 400    // hidden width
#define BN_EPS 1e-3f

#define KT0 2     // layer-0 K=64  -> 2 chunks of K32
#define KTH 13    // layers 1/2 K=400 padded to 416 -> 13 chunks of K32

typedef __attribute__((ext_vector_type(8))) short bf16x8;
typedef __attribute__((ext_vector_type(4))) float f32x4;

// ---- fp32 -> bf16 hi/lo split ----
__device__ __forceinline__ ushort bf16_rn(float x) {
    __hip_bfloat16 h = __float2bfloat16(x);
    union { __hip_bfloat16 b; ushort u; } c; c.b = h; return c.u;
}
__device__ __forceinline__ void split2(float x, ushort& hi, ushort& lo) {
    unsigned xb = __float_as_uint(x);
    unsigned hb = xb & 0xFFFF0000u;
    hi = (ushort)(hb >> 16);
    lo = bf16_rn(x - __uint_as_float(hb));
}

// async global->LDS, 16 B per lane: LDS dst is wave-uniform base + lane*16,
// global src is per-lane (base + lane*16 passed in).
__device__ __forceinline__ void gload_lds16(const ushort* g, ushort* l) {
    __builtin_amdgcn_global_load_lds(
        (const __attribute__((address_space(1))) void*)g,
        (__attribute__((address_space(3))) void*)l,
        16, 0, 0);
}

// MFMA 16x16x32 bf16 fragment layout. Panels: [tile16][kt32][lane 64][j 8]
// ushorts; one (tile,kt) chunk = 512 ushorts = 1 KB.
__device__ __forceinline__ size_t panel_idx(int p, int k, int KT) {
    int lane_ = (p & 15) + 16 * ((k >> 2) & 3);
    int j_    = (k & 3) + 4 * ((k >> 4) & 1);
    return (((size_t)((p >> 4) * KT + (k >> 5)) * 64) + lane_) * 8 + j_;
}

// ---------------------------------------------------------------------------
// Front kernel (verified round-2/8 body, R=4):
//  blocks [0,1024): gather + l_z + l_p -> A0 panels (hi/lo)
//  blocks [1024,1422): prepack W0/W1/W2 -> B panels; fold BN -> AC arrays
// ---------------------------------------------------------------------------
__global__ __launch_bounds__(256) void fused_front_kernel(
    const int*   __restrict__ fidx,
    const float* __restrict__ emb,
    const float* __restrict__ lin_w,
    const float* __restrict__ quad_w,
    const float* __restrict__ W0, const float* __restrict__ W1, const float* __restrict__ W2,
    const float* __restrict__ b0_, const float* __restrict__ g0_, const float* __restrict__ be0_,
    const float* __restrict__ rm0_, const float* __restrict__ rv0_,
    const float* __restrict__ b1_, const float* __restrict__ g1_, const float* __restrict__ be1_,
    const float* __restrict__ rm1_, const float* __restrict__ rv1_,
    const float* __restrict__ b2_, const float* __restrict__ g2_, const float* __restrict__ be2_,
    const float* __restrict__ rm2_, const float* __restrict__ rv2_,
    ushort* __restrict__ A0h, ushort* __restrict__ A0l,
    ushort* __restrict__ B0h, ushort* __restrict__ B0l,
    ushort* __restrict__ B1h, ushort* __restrict__ B1l,
    ushort* __restrict__ B2h, ushort* __restrict__ B2l,
    float* __restrict__ AC)
{
    if (blockIdx.x >= TB / 4) {
        int tid = (blockIdx.x - TB / 4) * 256 + threadIdx.x;
        const int NW0 = 64 * 112, NW = 416 * 112;
        if (tid < NW0 + 2 * NW) {
            const float* W; ushort *Ph, *Pl; int k, n4, K, KT;
            if (tid < NW0) {
                W = W0; Ph = B0h; Pl = B0l; k = tid / 112; n4 = tid % 112; K = 64; KT = KT0;
            } else if (tid < NW0 + NW) {
                int u = tid - NW0;
                W = W1; Ph = B1h; Pl = B1l; k = u / 112; n4 = u % 112; K = TH; KT = KTH;
            } else {
                int u = tid - NW0 - NW;
                W = W2; Ph = B2h; Pl = B2l; k = u / 112; n4 = u % 112; K = TH; KT = KTH;
            }
            int n0 = n4 * 4;
            float4 w = make_float4(0.f, 0.f, 0.f, 0.f);
            if (k < K && n0 < TH)
                w = *(const float4*)&W[(size_t)k * TH + n0];
            float vals[4] = {w.x, w.y, w.z, w.w};
            #pragma unroll
            for (int i = 0; i < 4; ++i) {
                ushort hi, lo; split2(vals[i], hi, lo);
                size_t idx = panel_idx(n0 + i, k, KT);
                Ph[idx] = hi; Pl[idx] = lo;
            }
        } else if (tid < NW0 + 2 * NW + 3 * 448) {
            int u = tid - NW0 - 2 * NW;
            int layer = u / 448, h = u % 448;
            const float *gp, *bep, *rmp, *rvp, *bp;
            if (layer == 0)      { gp = g0_; bep = be0_; rmp = rm0_; rvp = rv0_; bp = b0_; }
            else if (layer == 1) { gp = g1_; bep = be1_; rmp = rm1_; rvp = rv1_; bp = b1_; }
            else                 { gp = g2_; bep = be2_; rmp = rm2_; rvp = rv2_; bp = b2_; }
            float aj = 0.f, cj = 0.f;
            if (h < TH) {
                aj = gp[h] * rsqrtf(rvp[h] + BN_EPS);
                cj = (bp[h] - rmp[h]) * aj + bep[h];
            }
            AC[layer * 896 + h] = aj;
            AC[layer * 896 + 448 + h] = cj;
        }
        return;
    }

    // ---------------- gather + product path ----------------
    constexpr int R = 4;
    __shared__ float e_s[R][TN * TM];
    __shared__ int   idx_s[R][TN];
    __shared__ float s_s[R][TN];

    const int t  = threadIdx.x;
    const int b0 = blockIdx.x * R;

    if (t < R * TN) {
        int r = t / TN, n = t - r * TN;
        idx_s[r][n] = fidx[(b0 + r) * TN + n];
    }
    __syncthreads();

    for (int r = 0; r < R; ++r) {
        for (int k4 = t; k4 < TN * TM / 4; k4 += 256) {
            int n = k4 >> 3;
            long long base = (long long)idx_s[r][n] * TM + ((k4 & 7) << 2);
            *(float4*)&e_s[r][k4 * 4] = *(const float4*)&emb[base];
        }
    }
    __syncthreads();

    // l_z
    {
        const int d = t >> 3, j = t & 7;
        float acc[R] = {0.f, 0.f, 0.f, 0.f};
        const float* lw_base = lin_w + d * (TN * TM);
        #pragma unroll 4
        for (int i = 0; i < TN; ++i) {
            float4 lw = *(const float4*)&lw_base[i * 32 + j * 4];
            #pragma unroll
            for (int r = 0; r < R; ++r) {
                float4 e4 = *(const float4*)&e_s[r][i * 32 + j * 4];
                acc[r] = fmaf(lw.x, e4.x, acc[r]);
                acc[r] = fmaf(lw.y, e4.y, acc[r]);
                acc[r] = fmaf(lw.z, e4.z, acc[r]);
                acc[r] = fmaf(lw.w, e4.w, acc[r]);
            }
        }
        #pragma unroll
        for (int off = 1; off < 8; off <<= 1)
            #pragma unroll
            for (int r = 0; r < R; ++r)
                acc[r] += __shfl_xor(acc[r], off);
        if (j == 0) {
            #pragma unroll
            for (int r = 0; r < R; ++r) {
                ushort hi, lo; split2(acc[r], hi, lo);
                size_t idx = panel_idx(b0 + r, d, KT0);
                A0h[idx] = hi; A0l[idx] = lo;
            }
        }
    }

    // s[n] = sum_m e^2
    {
        int r = t >> 6, lane = t & 63;
        if (lane < TN) {
            float s = 0.f;
            #pragma unroll
            for (int mm = 0; mm < TM; ++mm) {
                float v = e_s[r][lane * TM + ((lane + mm) & 31)];
                s = fmaf(v, v, s);
            }
            s_s[r][lane] = s;
        }
    }
    __syncthreads();

    // l_p
    if (t < R * TD) {
        int r = t >> 5, d = t & 31;
        float accv = 0.f;
        for (int n = 0; n < TN; ++n) {
            float q = quad_w[d * TN + n];
            accv = fmaf(s_s[r][n], q * q, accv);
        }
        ushort hi, lo; split2(accv, hi, lo);
        size_t idx = panel_idx(b0 + r, TD + d, KT0);
        A0h[idx] = hi; A0l[idx] = lo;
    }
}

// ---------------------------------------------------------------------------
// GEMM v7: 64x64 tile, 4 waves (2M x 2N quadrants of 32x32), XCD swizzle.
// NEW: per-kt 16 KB of A/B chunks staged into LDS once per block via
// global_load_lds (double-buffered, one barrier/kt) -> halves L2 traffic
// (waves previously duplicated A reads across nsel and B reads across msel).
// Chunk c (0..15): c<8 -> A tile mt=c>>1, part=c&1 (hi/lo); c>=8 -> B tile
// nt=(c-8)>>1. LDS chunk = 1 KB = 64 lanes x 16 B (matches panel layout).
// OUTMODE 0: BN+ReLU -> repack into next layer's A panels (ysm aliased onto
// the stage buffer). OUTMODE 1: BN+ReLU -> Wout dot -> partials to P.
// ---------------------------------------------------------------------------
template <int KT, int OUTMODE>
__global__ __launch_bounds__(256) void gemm_layer_v7(
    const ushort* __restrict__ Ah, const ushort* __restrict__ Al,
    const ushort* __restrict__ Bh, const ushort* __restrict__ Bl,
    const float* __restrict__ ACl,
    ushort* __restrict__ Nh, ushort* __restrict__ Nl,
    const float* __restrict__ Wout,
    float* __restrict__ P)
{
    __shared__ ushort stage[2][16 * 512];   // 2 x 16 KB double buffer

    const int lane = threadIdx.x & 63;
    const int wv   = threadIdx.x >> 6;      // 0..3
    const int msel = wv >> 1;               // M half
    const int nsel = wv & 1;                // N half

    // XCD-aware bijective swizzle over 448 blocks (bm 0..63, bn 0..6)
    const int orig = blockIdx.x;
    const int xcd  = orig & 7;
    const int slot = orig >> 3;             // 0..55
    const int bm   = (slot & 7) * 8 + xcd;  // 0..63
    const int bn   = slot >> 3;             // 0..6

    // Per-wave staging assignment: 4 chunks each
    const ushort* csrc[4];
    int coff[4];
    #pragma unroll
    for (int i = 0; i < 4; ++i) {
        int c = wv * 4 + i;
        bool isA = c < 8;
        int tl  = isA ? (c >> 1) : ((c - 8) >> 1);
        bool lo = c & 1;
        const ushort* base = isA ? (lo ? Al : Ah) : (lo ? Bl : Bh);
        int tileIdx = isA ? (bm * 4 + tl) : (bn * 4 + tl);
        csrc[i] = base + (size_t)tileIdx * KT * 512 + (size_t)lane * 8;
        coff[i] = c * 512;
    }

    f32x4 acc[2][2];
    #pragma unroll
    for (int m = 0; m < 2; ++m)
        #pragma unroll
        for (int n = 0; n < 2; ++n)
            acc[m][n] = (f32x4){0.f, 0.f, 0.f, 0.f};

    // prologue: stage kt=0 into buf0
    #pragma unroll
    for (int i = 0; i < 4; ++i)
        gload_lds16(csrc[i], &stage[0][coff[i]]);
    __syncthreads();

    for (int kt = 0; kt < KT; ++kt) {
        const int cur = kt & 1;
        if (kt + 1 < KT) {
            #pragma unroll
            for (int i = 0; i < 4; ++i)
                gload_lds16(csrc[i] + (size_t)(kt + 1) * 512,
                            &stage[cur ^ 1][coff[i]]);
        }
        const ushort* L = &stage[cur][0];
        bf16x8 ah[2], al[2], bh[2], bl[2];
        #pragma unroll
        for (int m = 0; m < 2; ++m) {
            int mt = msel * 2 + m;
            ah[m] = *(const bf16x8*)&L[(mt * 2 + 0) * 512 + lane * 8];
            al[m] = *(const bf16x8*)&L[(mt * 2 + 1) * 512 + lane * 8];
        }
        #pragma unroll
        for (int n = 0; n < 2; ++n) {
            int nt = nsel * 2 + n;
            bh[n] = *(const bf16x8*)&L[(8 + nt * 2 + 0) * 512 + lane * 8];
            bl[n] = *(const bf16x8*)&L[(8 + nt * 2 + 1) * 512 + lane * 8];
        }
        #pragma unroll
        for (int m = 0; m < 2; ++m)
            #pragma unroll
            for (int n = 0; n < 2; ++n) {
                acc[m][n] = __builtin_amdgcn_mfma_f32_16x16x32_bf16(ah[m], bh[n], acc[m][n], 0, 0, 0);
                acc[m][n] = __builtin_amdgcn_mfma_f32_16x16x32_bf16(ah[m], bl[n], acc[m][n], 0, 0, 0);
                acc[m][n] = __builtin_amdgcn_mfma_f32_16x16x32_bf16(al[m], bh[n], acc[m][n], 0, 0, 0);
            }
        __syncthreads();   // drains staged loads; protects buffer swap
    }

    const int col = lane & 15, rq = (lane >> 4) << 2;

    if constexpr (OUTMODE == 0) {
        float (*ysm)[68] = (float (*)[68])(void*)&stage[0][0];  // 17.4 KB alias
        #pragma unroll
        for (int m = 0; m < 2; ++m)
            #pragma unroll
            for (int n = 0; n < 2; ++n) {
                int h = bn * 64 + (nsel * 2 + n) * 16 + col;
                float aj = ACl[h], cj = ACl[448 + h];
                #pragma unroll
                for (int r = 0; r < 4; ++r)
                    ysm[msel * 32 + m * 16 + rq + r][(nsel * 2 + n) * 16 + col] =
                        fmaxf(fmaf(acc[m][n][r], aj, cj), 0.f);
            }
        __syncthreads();

        const int ck = wv & 1;
        const int kt32 = bn * 2 + ck;
        if (kt32 < KTH) {
            #pragma unroll
            for (int mi = 0; mi < 2; ++mi) {
                int mtl = (wv >> 1) * 2 + mi;    // 0..3
                int row_l = mtl * 16 + (lane & 15);
                int kb = ck * 32 + rq;
                float4 v0 = *(const float4*)&ysm[row_l][kb];
                float4 v1 = *(const float4*)&ysm[row_l][kb + 16];
                ushort h_[8], l_[8];
                split2(v0.x, h_[0], l_[0]); split2(v0.y, h_[1], l_[1]);
                split2(v0.z, h_[2], l_[2]); split2(v0.w, h_[3], l_[3]);
                split2(v1.x, h_[4], l_[4]); split2(v1.y, h_[5], l_[5]);
                split2(v1.z, h_[6], l_[6]); split2(v1.w, h_[7], l_[7]);
                uint4 H, L2;
                H.x = (uint)h_[0] | ((uint)h_[1] << 16);
                H.y = (uint)h_[2] | ((uint)h_[3] << 16);
                H.z = (uint)h_[4] | ((uint)h_[5] << 16);
                H.w = (uint)h_[6] | ((uint)h_[7] << 16);
                L2.x = (uint)l_[0] | ((uint)l_[1] << 16);
                L2.y = (uint)l_[2] | ((uint)l_[3] << 16);
                L2.z = (uint)l_[4] | ((uint)l_[5] << 16);
                L2.w = (uint)l_[6] | ((uint)l_[7] << 16);
                size_t base = (((size_t)(bm * 4 + mtl) * KTH + kt32) * 64 + lane) * 8;
                *(uint4*)(Nh + base) = H;
                *(uint4*)(Nl + base) = L2;
            }
        }
    } else {
        // Fused final-layer epilogue: y = relu(bn(acc)); partial = sum_h y*Wout[h]
        float partial[2][4] = {{0.f,0.f,0.f,0.f},{0.f,0.f,0.f,0.f}};
        #pragma unroll
        for (int m = 0; m < 2; ++m)
            #pragma unroll
            for (int n = 0; n < 2; ++n) {
                int h = bn * 64 + (nsel * 2 + n) * 16 + col;
                float aj = ACl[h], cj = ACl[448 + h];
                float wv_ = (h < TH) ? Wout[h] : 0.f;
                #pragma unroll
                for (int r = 0; r < 4; ++r) {
                    float y = fmaxf(fmaf(acc[m][n][r], aj, cj), 0.f);
                    partial[m][r] = fmaf(y, wv_, partial[m][r]);
                }
            }
        #pragma unroll
        for (int off = 1; off < 16; off <<= 1)
            #pragma unroll
            for (int m = 0; m < 2; ++m)
                #pragma unroll
                for (int r = 0; r < 4; ++r)
                    partial[m][r] += __shfl_xor(partial[m][r], off);
        if (col == 0) {
            #pragma unroll
            for (int m = 0; m < 2; ++m)
                #pragma unroll
                for (int r = 0; r < 4; ++r)
                    P[(size_t)(bm * 64 + msel * 32 + m * 16 + rq + r) * 16
                      + bn * 2 + nsel] = partial[m][r];
        }
    }
}

// ---------------------------------------------------------------------------
// fin: out[row] = sigmoid(sum_{i<14} P[row][i] + bout), float4 loads
// ---------------------------------------------------------------------------
__global__ __launch_bounds__(256) void fin_kernel(
    const float* __restrict__ P, const float* __restrict__ bout,
    float* __restrict__ out)
{
    int row = blockIdx.x * 256 + threadIdx.x;
    const float4* p = (const float4*)(P + (size_t)row * 16);
    float4 p0 = p[0], p1 = p[1], p2 = p[2], p3 = p[3];
    float s = bout[0]
            + p0.x + p0.y + p0.z + p0.w
            + p1.x + p1.y + p1.z + p1.w
            + p2.x + p2.y + p2.z + p2.w
            + p3.x + p3.y;
    out[row] = 1.f / (1.f + expf(-s));
}

// ---------------------------------------------------------------------------
extern "C" void kernel_launch(void* const* d_in, const int* in_sizes, int n_in,
                              void* d_out, int out_size, void* d_ws, size_t ws_size,
                              hipStream_t stream) {
    const int*   fidx   = (const int*)  d_in[0];
    const float* emb    = (const float*)d_in[2];
    const float* lin_w  = (const float*)d_in[3];
    const float* quad_w = (const float*)d_in[4];

    const float* W0  = (const float*)d_in[5];
    const float* b0  = (const float*)d_in[6];
    const float* g0  = (const float*)d_in[7];
    const float* be0 = (const float*)d_in[8];
    const float* rm0 = (const float*)d_in[9];
    const float* rv0 = (const float*)d_in[10];

    const float* W1  = (const float*)d_in[11];
    const float* b1  = (const float*)d_in[12];
    const float* g1  = (const float*)d_in[13];
    const float* be1 = (const float*)d_in[14];
    const float* rm1 = (const float*)d_in[15];
    const float* rv1 = (const float*)d_in[16];

    const float* W2  = (const float*)d_in[17];
    const float* b2  = (const float*)d_in[18];
    const float* g2  = (const float*)d_in[19];
    const float* be2 = (const float*)d_in[20];
    const float* rm2 = (const float*)d_in[21];
    const float* rv2 = (const float*)d_in[22];

    const float* Wout = (const float*)d_in[23];
    const float* bout = (const float*)d_in[24];

    const size_t SZ_A0 = (size_t)256 * KT0 * 512;
    const size_t SZ_A  = (size_t)256 * KTH * 512;
    const size_t SZ_B0 = (size_t)28  * KT0 * 512;
    const size_t SZ_B  = (size_t)28  * KTH * 512;

    ushort* p = (ushort*)d_ws;
    ushort *A0h = p; p += SZ_A0; ushort *A0l = p; p += SZ_A0;
    ushort *A1h = p; p += SZ_A;  ushort *A1l = p; p += SZ_A;
    ushort *A2h = p; p += SZ_A;  ushort *A2l = p; p += SZ_A;
    ushort *B0h = p; p += SZ_B0; ushort *B0l = p; p += SZ_B0;
    ushort *B1h = p; p += SZ_B;  ushort *B1l = p; p += SZ_B;
    ushort *B2h = p; p += SZ_B;  ushort *B2l = p; p += SZ_B;
    float*  AC  = (float*)p;                 // 3 * 896 floats
    float*  Pst = AC + 3 * 896;              // 4096 x 16 partials

    fused_front_kernel<<<TB / 4 + 398, 256, 0, stream>>>(
        fidx, emb, lin_w, quad_w, W0, W1, W2,
        b0, g0, be0, rm0, rv0,
        b1, g1, be1, rm1, rv1,
        b2, g2, be2, rm2, rv2,
        A0h, A0l, B0h, B0l, B1h, B1l, B2h, B2l, AC);

    gemm_layer_v7<KT0, 0><<<448, 256, 0, stream>>>(
        A0h, A0l, B0h, B0l, AC + 0, A1h, A1l, nullptr, nullptr);
    gemm_layer_v7<KTH, 0><<<448, 256, 0, stream>>>(
        A1h, A1l, B1h, B1l, AC + 896, A2h, A2l, nullptr, nullptr);
    gemm_layer_v7<KTH, 1><<<448, 256, 0, stream>>>(
        A2h, A2l, B2h, B2l, AC + 1792, nullptr, nullptr, Wout, Pst);

    fin_kernel<<<TB / 256, 256, 0, stream>>>(Pst, bout, (float*)d_out);
}